// Round 9
// baseline (487.806 us; speedup 1.0000x reference)
//
#include <hip/hip_runtime.h>
#include <hip/hip_fp16.h>

// N = 100000 nodes, E = 1600000 edges, IN=256, HID=128, OUT=64

typedef __attribute__((ext_vector_type(8))) short short8;
typedef __attribute__((ext_vector_type(4))) float f32x4;

constexpr int SLOT   = 48;    // per-node row: [0]=count, [1..47]=neighbor ids
constexpr int NBUK   = 256;   // dst-range buckets
constexpr int BCAP   = 8000;  // per-bucket edge capacity (mean 6250, +22 sigma)
constexpr int NPB    = 391;   // nodes per bucket (256*391 >= 100000)
constexpr int EPB    = 8192;  // edges per bin block (4 chunks)
constexpr int EPT    = 32;    // edges per thread in bin block

struct alignas(16) H8 { __half2 h[4]; };

static __device__ __forceinline__ unsigned short f2bf(float f) {
    unsigned u = __float_as_uint(f);
    unsigned r = (u + 0x7fff + ((u >> 16) & 1)) >> 16;   // RNE
    return (unsigned short)r;
}
static __device__ __forceinline__ float bf2f(unsigned short h) {
    return __uint_as_float(((unsigned)h) << 16);
}
static __device__ __forceinline__ void unpackH8(const H8& hv, float* av) {
#pragma unroll
    for (int q = 0; q < 4; ++q) {
        float2 f = __half22float2(hv.h[q]);
        av[2 * q] = f.x; av[2 * q + 1] = f.y;
    }
}
static __device__ __forceinline__ void splitA(const float* av, short8& hi, short8& lo) {
#pragma unroll
    for (int i = 0; i < 8; ++i) {
        unsigned short h = f2bf(av[i]);
        hi[i] = (short)h;
        lo[i] = (short)f2bf(av[i] - bf2f(h));
    }
}

// ------------------------------------------------------- weight pre-pack ---
// P[(k0*NF+cn)*1024 + sel*512 + lane*8 + i], k = k0*32+(lane>>4)*8+i,
// n = cn*16+(lane&15), sel 0=hi 1=lo.
static __device__ __forceinline__ void pack_one(
    const float* __restrict__ W, unsigned short* __restrict__ P,
    int Kd, int Nd, int idx)
{
    int k = idx / Nd, nn = idx % Nd;
    float w = W[idx];
    unsigned short hi = f2bf(w);
    unsigned short lo = f2bf(w - bf2f(hi));
    int k0 = k >> 5, kin = k & 31, bk = kin >> 3, i = kin & 7;
    int lane = (nn & 15) + (bk << 4);
    int cn = nn >> 4, NF = Nd >> 4;
    size_t base = (size_t)(k0 * NF + cn) * 1024;
    P[base + lane * 8 + i] = hi;
    P[base + 512 + lane * 8 + i] = lo;
}

__global__ void pack_all_k(const float* __restrict__ W1, const float* __restrict__ W2,
                           const float* __restrict__ Wf1, const float* __restrict__ Wf2,
                           unsigned short* __restrict__ W1p, unsigned short* __restrict__ W2p,
                           unsigned short* __restrict__ Wf1p, unsigned short* __restrict__ Wf2p,
                           int* __restrict__ gcur) {
    int gid = blockIdx.x * blockDim.x + threadIdx.x;
    const int n1 = 256 * 128, n2 = n1 + 128 * 128, n3 = n2 + 128 * 128, n4 = n3 + 128 * 64;
    if      (gid < n1) pack_one(W1,  W1p,  256, 128, gid);
    else if (gid < n2) pack_one(W2,  W2p,  128, 128, gid - n1);
    else if (gid < n3) pack_one(Wf1, Wf1p, 128, 128, gid - n2);
    else if (gid < n4) pack_one(Wf2, Wf2p, 128, 64,  gid - n3);
    else if (gid < n4 + NBUK) gcur[gid - n4] = 0;
}

// --------------------------------------------------------- MFMA GEMM -------
// C[M,N] = A[M,K] @ B[K,N] via bf16 hi/lo split (hh+hl+lh), fp32 accum.
// 4 waves, BM=128 (32 rows/wave), BN=N. No LDS, no barriers. (gemm1 only)
template<int K, int N, bool HOUT>
__global__ __launch_bounds__(256) void mgemm_k(
    const float* __restrict__ A, const unsigned short* __restrict__ Bp,
    void* __restrict__ Cv, int M)
{
    constexpr int NF = N / 16;
    constexpr int KS = K / 32;
    const int lane = threadIdx.x & 63;
    const int wid  = threadIdx.x >> 6;
    const int m16  = lane & 15;
    const int kg   = lane >> 4;
    const int rowB = blockIdx.x * 128 + wid * 32;

    f32x4 acc[2][NF];
#pragma unroll
    for (int rm = 0; rm < 2; ++rm)
#pragma unroll
        for (int cn = 0; cn < NF; ++cn)
            acc[rm][cn] = (f32x4){0.f, 0.f, 0.f, 0.f};

    const short8* bp8 = (const short8*)Bp;

    for (int ks = 0; ks < KS; ++ks) {
        short8 ahi[2], alo[2];
#pragma unroll
        for (int rm = 0; rm < 2; ++rm) {
            int r = rowB + rm * 16 + m16;
            if (r >= M) r = M - 1;                     // stores are guarded
            const float* ap = A + (size_t)r * K + ks * 32 + kg * 8;
            float4 a0 = *(const float4*)ap;
            float4 a1 = *(const float4*)(ap + 4);
            float av[8] = {a0.x, a0.y, a0.z, a0.w, a1.x, a1.y, a1.z, a1.w};
            splitA(av, ahi[rm], alo[rm]);
        }
#pragma unroll
        for (int cn = 0; cn < NF; ++cn) {
            size_t fb = (size_t)(ks * NF + cn) * 128 + lane;
            short8 bhi = bp8[fb];
            short8 blo = bp8[fb + 64];
#pragma unroll
            for (int rm = 0; rm < 2; ++rm) {
                acc[rm][cn] = __builtin_amdgcn_mfma_f32_16x16x32_bf16(ahi[rm], bhi, acc[rm][cn], 0, 0, 0);
                acc[rm][cn] = __builtin_amdgcn_mfma_f32_16x16x32_bf16(ahi[rm], blo, acc[rm][cn], 0, 0, 0);
                acc[rm][cn] = __builtin_amdgcn_mfma_f32_16x16x32_bf16(alo[rm], bhi, acc[rm][cn], 0, 0, 0);
            }
        }
    }
#pragma unroll
    for (int rm = 0; rm < 2; ++rm)
#pragma unroll
        for (int r = 0; r < 4; ++r) {
            int row = rowB + rm * 16 + kg * 4 + r;
            if (row < M) {
#pragma unroll
                for (int cn = 0; cn < NF; ++cn) {
                    float v = acc[rm][cn][r];
                    if (HOUT) ((__half*)Cv)[(size_t)row * N + cn * 16 + m16] = __float2half(v);
                    else      ((float*)Cv)[(size_t)row * N + cn * 16 + m16] = v;
                }
            }
        }
}

// ------------------------------------------------- binning (standalone) ----
// 196 blocks x 8192 edges; edges reg-buffered; hist accumulated in LDS over
// all 4 chunks -> ONE global-atomic round per block (196 per-address chains).
__global__ __launch_bounds__(256) void bin_k(
    const int* __restrict__ esrc, const int* __restrict__ edst,
    int2* __restrict__ bins, int* __restrict__ gcur, int E)
{
    __shared__ int hist[NBUK];
    __shared__ int bpos[NBUK];
    const int base = blockIdx.x * EPB + threadIdx.x;
    hist[threadIdx.x] = 0;
    __syncthreads();
    int2 es[EPT]; int pl[EPT];
#pragma unroll
    for (int i = 0; i < EPT; ++i) {
        int e = base + i * 256;
        bool ok = (e < E);
        es[i] = make_int2(ok ? esrc[e] : 0, ok ? edst[e] : -1);
    }
#pragma unroll
    for (int i = 0; i < EPT; ++i) {
        int d = es[i].y;
        if (d >= 0) pl[i] = atomicAdd(&hist[(unsigned)d / (unsigned)NPB], 1);
    }
    __syncthreads();
    {
        int h = hist[threadIdx.x];
        bpos[threadIdx.x] = h ? atomicAdd(&gcur[threadIdx.x], h) : 0;
    }
    __syncthreads();
#pragma unroll
    for (int i = 0; i < EPT; ++i) {
        int d = es[i].y;
        if (d >= 0) {
            int b = (unsigned)d / (unsigned)NPB;
            int p = bpos[b] + pl[i];
            if (p < BCAP) bins[(size_t)b * BCAP + p] = es[i];
        }
    }
}

// ------------------------------------- fill: one workgroup per dst bucket --
__global__ __launch_bounds__(1024) void fill2_k(
    const int2* __restrict__ bins, const int* __restrict__ gcur,
    int* __restrict__ slot, float* __restrict__ dinv, int n)
{
    const int b = blockIdx.x;
    const int base = b * NPB;
    const int nn = min(NPB, n - base);
    if (nn <= 0) return;
    __shared__ int cnt[NPB];
    for (int i = threadIdx.x; i < nn; i += 1024) cnt[i] = 0;
    __syncthreads();
    int ec = gcur[b]; if (ec > BCAP) ec = BCAP;
    for (int i = threadIdx.x; i < ec; i += 1024) {
        int2 e = bins[(size_t)b * BCAP + i];
        int li = e.y - base;
        int p = atomicAdd(&cnt[li], 1);
        if (p < SLOT - 1) slot[(size_t)e.y * SLOT + 1 + p] = e.x;
    }
    __syncthreads();
    for (int i = threadIdx.x; i < nn; i += 1024) {
        int c = cnt[i];
        slot[(size_t)(base + i) * SLOT] = c;
        dinv[base + i] = 1.0f / sqrtf((float)(c + 1));
    }
}

// ----------------------------------------------- agg phase (into LDS tile) -
// tile[128][128] fp16, 16B chunks XOR-swizzled: chunk' = chunk ^ (row&7).
// SS=true : hs unscaled; row = relu(dn*(dn*hs[d] + sum dinv[s]*hs[s]) + b)
// SS=false: hs pre-scaled;  row = relu(dn*(hs[d] + sum hs[s]) + b)
template<bool SS>
static __device__ __forceinline__ void agg_phase(
    const H8* __restrict__ hs, const int* __restrict__ slot,
    const float* __restrict__ dinv, const float* __restrict__ bias,
    __half* __restrict__ tile, int rowB, int n)
{
    const int ln = threadIdx.x & 15;
    const float4 b0 = ((const float4*)bias)[ln * 2];
    const float4 b1 = ((const float4*)bias)[ln * 2 + 1];
    H8* t8 = (H8*)tile;
#pragma unroll 1
    for (int it = 0; it < 8; ++it) {
        int local = (threadIdx.x >> 4) + it * 16;
        int node = rowB + local;
        if (node >= n) node = n - 1;               // tile row still written
        const int* row = slot + (size_t)node * SLOT;
        int cnt = row[0]; if (cnt > SLOT - 1) cnt = SLOT - 1;
        float dn = dinv[node];

        float acc[8];
        {
            H8 v = hs[(size_t)node * 16 + ln];
            float sf = SS ? dn : 1.f;
            float av[8]; unpackH8(v, av);
#pragma unroll
            for (int q = 0; q < 8; ++q) acc[q] = av[q] * sf;
        }
        int j = 0;
        for (; j + 4 <= cnt; j += 4) {
            int s0 = row[1 + j], s1 = row[2 + j], s2 = row[3 + j], s3 = row[4 + j];
            float w0 = 1.f, w1 = 1.f, w2 = 1.f, w3 = 1.f;
            if (SS) { w0 = dinv[s0]; w1 = dinv[s1]; w2 = dinv[s2]; w3 = dinv[s3]; }
            H8 v0 = hs[(size_t)s0 * 16 + ln];
            H8 v1 = hs[(size_t)s1 * 16 + ln];
            H8 v2 = hs[(size_t)s2 * 16 + ln];
            H8 v3 = hs[(size_t)s3 * 16 + ln];
            float a0[8], a1[8], a2[8], a3[8];
            unpackH8(v0, a0); unpackH8(v1, a1); unpackH8(v2, a2); unpackH8(v3, a3);
#pragma unroll
            for (int q = 0; q < 8; ++q) {
                if (SS)
                    acc[q] = fmaf(w0, a0[q], fmaf(w1, a1[q], fmaf(w2, a2[q], fmaf(w3, a3[q], acc[q]))));
                else
                    acc[q] += (a0[q] + a1[q]) + (a2[q] + a3[q]);
            }
        }
        for (; j < cnt; ++j) {
            int s = row[1 + j];
            float w = SS ? dinv[s] : 1.f;
            H8 v = hs[(size_t)s * 16 + ln];
            float av[8]; unpackH8(v, av);
#pragma unroll
            for (int q = 0; q < 8; ++q) acc[q] = fmaf(w, av[q], acc[q]);
        }
        H8 r;
        r.h[0] = __floats2half2_rn(fmaxf(fmaf(acc[0], dn, b0.x), 0.f),
                                   fmaxf(fmaf(acc[1], dn, b0.y), 0.f));
        r.h[1] = __floats2half2_rn(fmaxf(fmaf(acc[2], dn, b0.z), 0.f),
                                   fmaxf(fmaf(acc[3], dn, b0.w), 0.f));
        r.h[2] = __floats2half2_rn(fmaxf(fmaf(acc[4], dn, b1.x), 0.f),
                                   fmaxf(fmaf(acc[5], dn, b1.y), 0.f));
        r.h[3] = __floats2half2_rn(fmaxf(fmaf(acc[6], dn, b1.z), 0.f),
                                   fmaxf(fmaf(acc[7], dn, b1.w), 0.f));
        t8[local * 16 + (ln ^ (local & 7))] = r;    // swizzled 16B store
    }
}

// --------------------------------------- gemm from LDS tile (swizzled A) ---
template<int K, int N>
static __device__ __forceinline__ void gemm_lds_acc(
    const __half* __restrict__ tile, const unsigned short* __restrict__ Bp,
    f32x4 acc[2][N / 16])
{
    constexpr int NF = N / 16;
    constexpr int KS = K / 32;
    const int lane = threadIdx.x & 63;
    const int wid  = threadIdx.x >> 6;
    const int m16  = lane & 15;
    const int kg   = lane >> 4;
    const H8* t8 = (const H8*)tile;
    const short8* bp8 = (const short8*)Bp;
#pragma unroll
    for (int rm = 0; rm < 2; ++rm)
#pragma unroll
        for (int cn = 0; cn < NF; ++cn)
            acc[rm][cn] = (f32x4){0.f, 0.f, 0.f, 0.f};
#pragma unroll
    for (int ks = 0; ks < KS; ++ks) {
        short8 ahi[2], alo[2];
#pragma unroll
        for (int rm = 0; rm < 2; ++rm) {
            int rl = wid * 32 + rm * 16 + m16;
            int ch = (ks * 4 + kg) ^ (rl & 7);
            float av[8]; unpackH8(t8[rl * 16 + ch], av);
            splitA(av, ahi[rm], alo[rm]);
        }
#pragma unroll
        for (int cn = 0; cn < NF; ++cn) {
            size_t fb = (size_t)(ks * NF + cn) * 128 + lane;
            short8 bhi = bp8[fb];
            short8 blo = bp8[fb + 64];
#pragma unroll
            for (int rm = 0; rm < 2; ++rm) {
                acc[rm][cn] = __builtin_amdgcn_mfma_f32_16x16x32_bf16(ahi[rm], bhi, acc[rm][cn], 0, 0, 0);
                acc[rm][cn] = __builtin_amdgcn_mfma_f32_16x16x32_bf16(ahi[rm], blo, acc[rm][cn], 0, 0, 0);
                acc[rm][cn] = __builtin_amdgcn_mfma_f32_16x16x32_bf16(alo[rm], bhi, acc[rm][cn], 0, 0, 0);
            }
        }
    }
}

// ------------------------- K_D: agg1 -> LDS -> gemm2 (*dinv) -> fp16 out ---
__global__ __launch_bounds__(256) void agg_gemm_k(
    const H8* __restrict__ hs, const int* __restrict__ slot,
    const float* __restrict__ dinv, const float* __restrict__ abias,
    const unsigned short* __restrict__ Bp, __half* __restrict__ Cout, int n)
{
    __shared__ __half tile[128 * 128];
    const int rowB = blockIdx.x * 128;
    agg_phase<true>(hs, slot, dinv, abias, tile, rowB, n);
    __syncthreads();
    f32x4 acc[2][8];
    gemm_lds_acc<128, 128>(tile, Bp, acc);
    const int lane = threadIdx.x & 63;
    const int m16 = lane & 15, kg = lane >> 4, wid = threadIdx.x >> 6;
#pragma unroll
    for (int rm = 0; rm < 2; ++rm)
#pragma unroll
        for (int r = 0; r < 4; ++r) {
            int row = rowB + wid * 32 + rm * 16 + kg * 4 + r;
            if (row < n) {
                float sc = dinv[row];
#pragma unroll
                for (int cn = 0; cn < 8; ++cn)
                    Cout[(size_t)row * 128 + cn * 16 + m16] = __float2half(acc[rm][cn][r] * sc);
            }
        }
}

// --------- K_E: agg2 -> LDS -> mlp1(relu) -> LDS -> mlp2 -> fp32 out -------
__global__ __launch_bounds__(256) void agg_mlp_k(
    const H8* __restrict__ hs, const int* __restrict__ slot,
    const float* __restrict__ dinv, const float* __restrict__ b2,
    const unsigned short* __restrict__ Wf1p, const float* __restrict__ bf1,
    const unsigned short* __restrict__ Wf2p, const float* __restrict__ bf2,
    float* __restrict__ out, int n)
{
    __shared__ __half tile[128 * 128];
    const int rowB = blockIdx.x * 128;
    agg_phase<false>(hs, slot, dinv, b2, tile, rowB, n);
    __syncthreads();
    const int lane = threadIdx.x & 63;
    const int m16 = lane & 15, kg = lane >> 4, wid = threadIdx.x >> 6;
    // mlp1: h3 = relu(h2 @ Wf1 + bf1), accumulate fully before overwriting tile
    {
        f32x4 acc[2][8];
        gemm_lds_acc<128, 128>(tile, Wf1p, acc);
        __syncthreads();                        // all tile reads complete
#pragma unroll
        for (int rm = 0; rm < 2; ++rm)
#pragma unroll
            for (int r = 0; r < 4; ++r) {
                int rl = wid * 32 + rm * 16 + kg * 4 + r;
#pragma unroll
                for (int cn = 0; cn < 8; ++cn) {
                    int col = cn * 16 + m16;
                    float v = fmaxf(acc[rm][cn][r] + bf1[col], 0.f);
                    int ch = (col >> 3) ^ (rl & 7);
                    tile[rl * 128 + (ch << 3) + (col & 7)] = __float2half(v);
                }
            }
    }
    __syncthreads();
    // mlp2: out = h3 @ Wf2 + bf2
    {
        f32x4 acc[2][4];
        gemm_lds_acc<128, 64>(tile, Wf2p, acc);
#pragma unroll
        for (int rm = 0; rm < 2; ++rm)
#pragma unroll
            for (int r = 0; r < 4; ++r) {
                int row = rowB + wid * 32 + rm * 16 + kg * 4 + r;
                if (row < n) {
#pragma unroll
                    for (int cn = 0; cn < 4; ++cn)
                        out[(size_t)row * 64 + cn * 16 + m16] = acc[rm][cn][r] + bf2[cn * 16 + m16];
                }
            }
    }
}

// ---------------------------------------------------------------- launch ---
extern "C" void kernel_launch(void* const* d_in, const int* in_sizes, int n_in,
                              void* d_out, int out_size, void* d_ws, size_t ws_size,
                              hipStream_t stream) {
    const float* x    = (const float*)d_in[0];
    const int*   eidx = (const int*)d_in[1];
    const float* W1   = (const float*)d_in[2];
    const float* b1   = (const float*)d_in[3];
    const float* W2   = (const float*)d_in[4];
    const float* b2   = (const float*)d_in[5];
    const float* Wf1  = (const float*)d_in[6];
    const float* bf1  = (const float*)d_in[7];
    const float* Wf2  = (const float*)d_in[8];
    const float* bf2  = (const float*)d_in[9];
    float* out = (float*)d_out;

    const int IN = 256;
    const int n = in_sizes[0] / IN;        // 100000
    const int E = in_sizes[1] / 2;         // 1600000
    const int* esrc = eidx;
    const int* edst = eidx + E;

    // workspace (bytes). bins alias bufH2: fill2 consumes bins before
    // agg_gemm_k writes bufH2. Total ~71.3 MB.
    char* ws = (char*)d_ws;
    __half* bufH1 = (__half*)(ws);                      // n*128 f16 = 25.6 MB
    __half* bufH2 = (__half*)(ws + 25600000);           // 25.6 MB
    int2*   bins  = (int2*)  (ws + 25600000);           // 256*8000*8 = 16.4 MB (alias)
    int*    slot  = (int*)   (ws + 51200000);           // n*48 i32 = 19.2 MB
    float*  dinv  = (float*) (ws + 70400000);           // n f32
    int*    gcur  = (int*)   (ws + 70800000);           // 256 ints
    unsigned short* W1p  = (unsigned short*)(ws + 70900000);   // 131072 B
    unsigned short* W2p  = (unsigned short*)(ws + 71040000);   //  65536 B
    unsigned short* Wf1p = (unsigned short*)(ws + 71110000);   //  65536 B
    unsigned short* Wf2p = (unsigned short*)(ws + 71180000);   //  32768 B

    const int TB = 256;
    const int nPack = 256*128 + 128*128 + 128*128 + 128*64 + NBUK;  // 73984
    const int gGemm = (n + 127) / 128;         // 782
    const int nBin  = (E + EPB - 1) / EPB;     // 196

    // K0: pack weights + zero bucket cursors
    pack_all_k<<<(nPack + TB - 1) / TB, TB, 0, stream>>>(W1, W2, Wf1, Wf2,
                                                          W1p, W2p, Wf1p, Wf2p, gcur);
    // K1: edge binning (standalone, 1 atomic round per block)
    bin_k<<<nBin, TB, 0, stream>>>(esrc, edst, bins, gcur, E);
    // K2: bucket-local fill (LDS counters) + dinv
    fill2_k<<<NBUK, 1024, 0, stream>>>(bins, gcur, slot, dinv, n);
    // K3: gemm1 (unscaled, fp16 out) -> bufH1
    mgemm_k<256, 128, true><<<gGemm, TB, 0, stream>>>(x, W1p, bufH1, n);
    // K4: agg1 + gemm2 fused -> bufH2
    agg_gemm_k<<<gGemm, TB, 0, stream>>>((const H8*)bufH1, slot, dinv, b1, W2p, bufH2, n);
    // K5: agg2 + mlp1 + mlp2 fused -> out
    agg_mlp_k<<<gGemm, TB, 0, stream>>>((const H8*)bufH2, slot, dinv, b2,
                                        Wf1p, bf1, Wf2p, bf2, out, n);
}

// Round 10
// 411.782 us; speedup vs baseline: 1.1846x; 1.1846x over previous
//
#include <hip/hip_runtime.h>
#include <hip/hip_fp16.h>

// N = 100000 nodes, E = 1600000 edges, IN=256, HID=128, OUT=64

typedef _Float16 __attribute__((ext_vector_type(8))) f16x8;
typedef __attribute__((ext_vector_type(4))) float f32x4;

constexpr int SLOT   = 48;    // per-node row: [0]=count, [1..47]=neighbor ids
constexpr int NBUK   = 256;   // dst-range buckets
constexpr int BCAP   = 8000;  // per-bucket edge capacity (mean 6250, +22 sigma)
constexpr int NPB    = 391;   // nodes per bucket (256*391 >= 100000)
constexpr int EPB    = 8192;  // edges per bin block
constexpr int EPT    = 32;    // edges per thread in bin block

struct alignas(16) H8 { __half2 h[4]; };

static __device__ __forceinline__ void unpackH8(const H8& hv, float* av) {
#pragma unroll
    for (int q = 0; q < 4; ++q) {
        float2 f = __half22float2(hv.h[q]);
        av[2 * q] = f.x; av[2 * q + 1] = f.y;
    }
}

// A-row loaders -> raw fp16 MFMA fragment (8 consecutive k-elements)
static __device__ __forceinline__ void loadAf16(const float* __restrict__ ap, f16x8& a) {
    float4 a0 = *(const float4*)ap;
    float4 a1 = *(const float4*)(ap + 4);
    a[0] = (_Float16)a0.x; a[1] = (_Float16)a0.y;
    a[2] = (_Float16)a0.z; a[3] = (_Float16)a0.w;
    a[4] = (_Float16)a1.x; a[5] = (_Float16)a1.y;
    a[6] = (_Float16)a1.z; a[7] = (_Float16)a1.w;
}
static __device__ __forceinline__ void loadAf16(const __half* __restrict__ ap, f16x8& a) {
    a = *(const f16x8*)ap;
}

// ------------------------------------------------------- weight pre-pack ---
// Pack W[K][N] fp32 -> fp16 in MFMA fragment layout:
// P[(k0*NF+cn)*512 + lane*8 + i], k = k0*32+(lane>>4)*8+i, n = cn*16+(lane&15).
static __device__ __forceinline__ void pack_one(
    const float* __restrict__ W, _Float16* __restrict__ P, int Nd, int idx)
{
    int k = idx / Nd, nn = idx % Nd;
    int k0 = k >> 5, kin = k & 31, bk = kin >> 3, i = kin & 7;
    int lane = (nn & 15) + (bk << 4);
    int cn = nn >> 4, NF = Nd >> 4;
    P[(size_t)(k0 * NF + cn) * 512 + lane * 8 + i] = (_Float16)W[idx];
}

__global__ void pack_all_k(const float* __restrict__ W1, const float* __restrict__ W2,
                           const float* __restrict__ Wf1, const float* __restrict__ Wf2,
                           _Float16* __restrict__ W1p, _Float16* __restrict__ W2p,
                           _Float16* __restrict__ Wf1p, _Float16* __restrict__ Wf2p,
                           int* __restrict__ gcur) {
    int gid = blockIdx.x * blockDim.x + threadIdx.x;
    const int n1 = 256 * 128, n2 = n1 + 128 * 128, n3 = n2 + 128 * 128, n4 = n3 + 128 * 64;
    if      (gid < n1) pack_one(W1,  W1p,  128, gid);
    else if (gid < n2) pack_one(W2,  W2p,  128, gid - n1);
    else if (gid < n3) pack_one(Wf1, Wf1p, 128, gid - n2);
    else if (gid < n4) pack_one(Wf2, Wf2p, 64,  gid - n3);
    else if (gid < n4 + NBUK) gcur[gid - n4] = 0;
}

// --------------------------------------------------- fp16 MFMA GEMM --------
// C[M,N] = A[M,K] @ B[K,N], single-pass mfma_f32_16x16x32_f16, fp32 accum.
// 4 waves, BM=128 (32 rows/wave), BN=N. No LDS, no barriers, no cvt VALU
// (fp16 A feeds MFMA raw; f32 A converts once per element).
template<typename AT, int K, int N, bool SCALE, bool BIAS, bool RELU, bool HOUT>
__global__ __launch_bounds__(256) void fgemm_k(
    const AT* __restrict__ A, const _Float16* __restrict__ Bp,
    const float* __restrict__ bias, const float* __restrict__ dinv,
    void* __restrict__ Cv, int M)
{
    constexpr int NF = N / 16;
    constexpr int KS = K / 32;
    const int lane = threadIdx.x & 63;
    const int wid  = threadIdx.x >> 6;
    const int m16  = lane & 15;
    const int kg   = lane >> 4;            // 0..3 (k-group)
    const int rowB = blockIdx.x * 128 + wid * 32;

    f32x4 acc[2][NF];
#pragma unroll
    for (int rm = 0; rm < 2; ++rm)
#pragma unroll
        for (int cn = 0; cn < NF; ++cn)
            acc[rm][cn] = (f32x4){0.f, 0.f, 0.f, 0.f};

    const f16x8* bp8 = (const f16x8*)Bp;

    for (int ks = 0; ks < KS; ++ks) {
        f16x8 a[2];
#pragma unroll
        for (int rm = 0; rm < 2; ++rm) {
            int r = rowB + rm * 16 + m16;
            if (r >= M) r = M - 1;                     // stores are guarded
            loadAf16(A + (size_t)r * K + ks * 32 + kg * 8, a[rm]);
        }
#pragma unroll
        for (int cn = 0; cn < NF; ++cn) {
            f16x8 b = bp8[(size_t)(ks * NF + cn) * 64 + lane];
#pragma unroll
            for (int rm = 0; rm < 2; ++rm)
                acc[rm][cn] = __builtin_amdgcn_mfma_f32_16x16x32_f16(a[rm], b, acc[rm][cn], 0, 0, 0);
        }
    }
    // epilogue: C row = rowB + rm*16 + kg*4 + r ; col = cn*16 + m16
#pragma unroll
    for (int rm = 0; rm < 2; ++rm)
#pragma unroll
        for (int r = 0; r < 4; ++r) {
            int row = rowB + rm * 16 + kg * 4 + r;
            if (row < M) {
                float sc = SCALE ? dinv[row] : 1.f;
#pragma unroll
                for (int cn = 0; cn < NF; ++cn) {
                    float v = acc[rm][cn][r];
                    if (SCALE) v *= sc;
                    if (BIAS)  v += bias[cn * 16 + m16];
                    if (RELU)  v = fmaxf(v, 0.f);
                    if (HOUT)
                        ((__half*)Cv)[(size_t)row * N + cn * 16 + m16] = __float2half(v);
                    else
                        ((float*)Cv)[(size_t)row * N + cn * 16 + m16] = v;
                }
            }
        }
}

// ------------------------------------------------- binning (standalone) ----
// 196 blocks x 8192 edges; edges reg-buffered; hist accumulated in LDS ->
// ONE global-atomic round per block.
__global__ __launch_bounds__(256) void bin_k(
    const int* __restrict__ esrc, const int* __restrict__ edst,
    int2* __restrict__ bins, int* __restrict__ gcur, int E)
{
    __shared__ int hist[NBUK];
    __shared__ int bpos[NBUK];
    const int base = blockIdx.x * EPB + threadIdx.x;
    hist[threadIdx.x] = 0;
    __syncthreads();
    int2 es[EPT]; int pl[EPT];
#pragma unroll
    for (int i = 0; i < EPT; ++i) {
        int e = base + i * 256;
        bool ok = (e < E);
        es[i] = make_int2(ok ? esrc[e] : 0, ok ? edst[e] : -1);
    }
#pragma unroll
    for (int i = 0; i < EPT; ++i) {
        int d = es[i].y;
        if (d >= 0) pl[i] = atomicAdd(&hist[(unsigned)d / (unsigned)NPB], 1);
    }
    __syncthreads();
    {
        int h = hist[threadIdx.x];
        bpos[threadIdx.x] = h ? atomicAdd(&gcur[threadIdx.x], h) : 0;
    }
    __syncthreads();
#pragma unroll
    for (int i = 0; i < EPT; ++i) {
        int d = es[i].y;
        if (d >= 0) {
            int b = (unsigned)d / (unsigned)NPB;
            int p = bpos[b] + pl[i];
            if (p < BCAP) bins[(size_t)b * BCAP + p] = es[i];
        }
    }
}

// ------------------------------------- fill: one workgroup per dst bucket --
__global__ __launch_bounds__(1024) void fill2_k(
    const int2* __restrict__ bins, const int* __restrict__ gcur,
    int* __restrict__ slot, float* __restrict__ dinv, int n)
{
    const int b = blockIdx.x;
    const int base = b * NPB;
    const int nn = min(NPB, n - base);
    if (nn <= 0) return;
    __shared__ int cnt[NPB];
    for (int i = threadIdx.x; i < nn; i += 1024) cnt[i] = 0;
    __syncthreads();
    int ec = gcur[b]; if (ec > BCAP) ec = BCAP;
    for (int i = threadIdx.x; i < ec; i += 1024) {
        int2 e = bins[(size_t)b * BCAP + i];
        int li = e.y - base;
        int p = atomicAdd(&cnt[li], 1);
        if (p < SLOT - 1) slot[(size_t)e.y * SLOT + 1 + p] = e.x;
    }
    __syncthreads();
    for (int i = threadIdx.x; i < nn; i += 1024) {
        int c = cnt[i];
        slot[(size_t)(base + i) * SLOT] = c;
        dinv[base + i] = 1.0f / sqrtf((float)(c + 1));
    }
}

// ----------------------------------------------------------- aggregation ---
// SS=true : hs unscaled; out = relu(dn*(dn*hs[d] + sum dinv[s]*hs[s]) + b)
// SS=false: hs pre-scaled by dinv[src]; out = relu(dn*(hs[d] + sum hs[s]) + b)
// fp16 in, fp16 out. 16 lanes x 16B per node. (R7's proven kernel, verbatim.)
template<bool SS>
__global__ __launch_bounds__(256) void agg_k(
    const H8* __restrict__ hs, const int* __restrict__ slot,
    const float* __restrict__ dinv, const float* __restrict__ bias,
    H8* __restrict__ out, int n)
{
    int t    = blockIdx.x * blockDim.x + threadIdx.x;
    int node = t >> 4;
    int ln   = threadIdx.x & 15;
    if (node >= n) return;
    const int* row = slot + (size_t)node * SLOT;
    int cnt = row[0]; if (cnt > SLOT - 1) cnt = SLOT - 1;
    float dn = dinv[node];

    float acc[8];
    {
        H8 v = hs[(size_t)node * 16 + ln];          // self-loop term
        float sf = SS ? dn : 1.f;
        float av[8]; unpackH8(v, av);
#pragma unroll
        for (int q = 0; q < 8; ++q) acc[q] = av[q] * sf;
    }
    int j = 0;
    for (; j + 4 <= cnt; j += 4) {
        int s0 = row[1 + j], s1 = row[2 + j], s2 = row[3 + j], s3 = row[4 + j];
        float w0 = 1.f, w1 = 1.f, w2 = 1.f, w3 = 1.f;
        if (SS) { w0 = dinv[s0]; w1 = dinv[s1]; w2 = dinv[s2]; w3 = dinv[s3]; }
        H8 v0 = hs[(size_t)s0 * 16 + ln];
        H8 v1 = hs[(size_t)s1 * 16 + ln];
        H8 v2 = hs[(size_t)s2 * 16 + ln];
        H8 v3 = hs[(size_t)s3 * 16 + ln];
        float a0[8], a1[8], a2[8], a3[8];
        unpackH8(v0, a0); unpackH8(v1, a1); unpackH8(v2, a2); unpackH8(v3, a3);
#pragma unroll
        for (int q = 0; q < 8; ++q) {
            if (SS)
                acc[q] = fmaf(w0, a0[q], fmaf(w1, a1[q], fmaf(w2, a2[q], fmaf(w3, a3[q], acc[q]))));
            else
                acc[q] += (a0[q] + a1[q]) + (a2[q] + a3[q]);
        }
    }
    for (; j < cnt; ++j) {
        int s = row[1 + j];
        float w = SS ? dinv[s] : 1.f;
        H8 v = hs[(size_t)s * 16 + ln];
        float av[8]; unpackH8(v, av);
#pragma unroll
        for (int q = 0; q < 8; ++q) acc[q] = fmaf(w, av[q], acc[q]);
    }
    float4 b0 = ((const float4*)bias)[ln * 2];
    float4 b1 = ((const float4*)bias)[ln * 2 + 1];
    H8 r;
    r.h[0] = __floats2half2_rn(fmaxf(fmaf(acc[0], dn, b0.x), 0.f),
                               fmaxf(fmaf(acc[1], dn, b0.y), 0.f));
    r.h[1] = __floats2half2_rn(fmaxf(fmaf(acc[2], dn, b0.z), 0.f),
                               fmaxf(fmaf(acc[3], dn, b0.w), 0.f));
    r.h[2] = __floats2half2_rn(fmaxf(fmaf(acc[4], dn, b1.x), 0.f),
                               fmaxf(fmaf(acc[5], dn, b1.y), 0.f));
    r.h[3] = __floats2half2_rn(fmaxf(fmaf(acc[6], dn, b1.z), 0.f),
                               fmaxf(fmaf(acc[7], dn, b1.w), 0.f));
    out[(size_t)node * 16 + ln] = r;
}

// ---------------------------------------------------------------- launch ---
extern "C" void kernel_launch(void* const* d_in, const int* in_sizes, int n_in,
                              void* d_out, int out_size, void* d_ws, size_t ws_size,
                              hipStream_t stream) {
    const float* x    = (const float*)d_in[0];
    const int*   eidx = (const int*)d_in[1];
    const float* W1   = (const float*)d_in[2];
    const float* b1   = (const float*)d_in[3];
    const float* W2   = (const float*)d_in[4];
    const float* b2   = (const float*)d_in[5];
    const float* Wf1  = (const float*)d_in[6];
    const float* bf1  = (const float*)d_in[7];
    const float* Wf2  = (const float*)d_in[8];
    const float* bf2  = (const float*)d_in[9];
    float* out = (float*)d_out;

    const int IN = 256;
    const int n = in_sizes[0] / IN;        // 100000
    const int E = in_sizes[1] / 2;         // 1600000
    const int* esrc = eidx;
    const int* edst = eidx + E;

    // workspace (bytes). bins alias bufH2: fill2 consumes bins before agg1
    // writes bufH2. Total ~71.1 MB.
    char* ws = (char*)d_ws;
    __half* bufH1 = (__half*)(ws);                      // n*128 f16 = 25.6 MB
    __half* bufH2 = (__half*)(ws + 25600000);           // 25.6 MB
    int2*   bins  = (int2*)  (ws + 25600000);           // 256*8000*8 = 16.4 MB (alias)
    int*    slot  = (int*)   (ws + 51200000);           // n*48 i32 = 19.2 MB
    float*  dinv  = (float*) (ws + 70400000);           // n f32
    int*    gcur  = (int*)   (ws + 70800000);           // 256 ints
    _Float16* W1p  = (_Float16*)(ws + 70900000);        // 65536 B
    _Float16* W2p  = (_Float16*)(ws + 70970000);        // 32768 B
    _Float16* Wf1p = (_Float16*)(ws + 71010000);        // 32768 B
    _Float16* Wf2p = (_Float16*)(ws + 71050000);        // 16384 B

    const int TB = 256;
    const int nPack = 256*128 + 128*128 + 128*128 + 128*64 + NBUK;  // 73984
    const int gGemm = (n + 127) / 128;         // 782
    const int nBin  = (E + EPB - 1) / EPB;     // 196
    const int gAgg  = (n * 16 + TB - 1) / TB;  // 6250

    // K0: pack weights (fp16 fragments) + zero bucket cursors
    pack_all_k<<<(nPack + TB - 1) / TB, TB, 0, stream>>>(W1, W2, Wf1, Wf2,
                                                          W1p, W2p, Wf1p, Wf2p, gcur);
    // K1: edge binning
    bin_k<<<nBin, TB, 0, stream>>>(esrc, edst, bins, gcur, E);
    // K2: bucket-local fill (LDS counters) + dinv
    fill2_k<<<NBUK, 1024, 0, stream>>>(bins, gcur, slot, dinv, n);
    // K3: gemm1 (f32 A -> fp16 cvt, unscaled, fp16 out) -> bufH1
    fgemm_k<float,  256, 128, false, false, false, true><<<gGemm, TB, 0, stream>>>(
        x, W1p, nullptr, nullptr, bufH1, n);
    // K4: agg1 (applies dinv[s], dinv[d]) -> bufH2 (kills bins)
    agg_k<true><<<gAgg, TB, 0, stream>>>((const H8*)bufH1, slot, dinv, b1, (H8*)bufH2, n);
    // K5: gemm2 (fp16 A, *dinv, fp16 out) -> bufH1
    fgemm_k<__half, 128, 128, true,  false, false, true><<<gGemm, TB, 0, stream>>>(
        (const __half*)bufH2, W2p, nullptr, dinv, bufH1, n);
    // K6: agg2 (pre-scaled) -> bufH2
    agg_k<false><<<gAgg, TB, 0, stream>>>((const H8*)bufH1, slot, dinv, b2, (H8*)bufH2, n);
    // K7: mlp1 (fp16 A, bias+relu, fp16 out) -> bufH1
    fgemm_k<__half, 128, 128, false, true,  true,  true><<<gGemm, TB, 0, stream>>>(
        (const __half*)bufH2, Wf1p, bf1, nullptr, bufH1, n);
    // K8: mlp2 (fp16 A, bias, fp32 out) -> out
    fgemm_k<__half, 128, 64,  false, true,  false, false><<<gGemm, TB, 0, stream>>>(
        (const __half*)bufH1, Wf2p, bf2, nullptr, out, n);
}